// Round 5
// baseline (313.480 us; speedup 1.0000x reference)
//
#include <hip/hip_runtime.h>

typedef __attribute__((ext_vector_type(8))) short short8;
typedef __attribute__((ext_vector_type(4))) float floatx4;

#define LOG2E     1.4426950408889634f
#define TWO_LOG2E 2.8853900817779268f

__device__ __forceinline__ unsigned short f2bf(float x) {
  union { float f; unsigned u; } v; v.f = x;
  unsigned r = v.u + 0x7fffu + ((v.u >> 16) & 1u);
  return (unsigned short)(r >> 16);
}
__device__ __forceinline__ unsigned cvt_pk(float lo, float hi) {
  unsigned r;
  asm("v_cvt_pk_bf16_f32 %0, %1, %2" : "=v"(r) : "v"(lo), "v"(hi));
  return r;
}
__device__ __forceinline__ float bfp_lo(unsigned p) { return __builtin_bit_cast(float, p << 16); }
__device__ __forceinline__ float bfp_hi(unsigned p) { return __builtin_bit_cast(float, p & 0xffff0000u); }
// s pre-scaled by log2e: sigmoid(x) = 1/(1+2^-s)
__device__ __forceinline__ float sigm_fast(float s) {
  return __builtin_amdgcn_rcpf(1.f + __builtin_amdgcn_exp2f(-s));
}
// y pre-scaled by 2*log2e: tanh(x) = 1 - 2/(1+2^y)
__device__ __forceinline__ float tanh_fast(float y) {
  return fmaf(-2.f, __builtin_amdgcn_rcpf(1.f + __builtin_amdgcn_exp2f(y)), 1.f);
}
__device__ __forceinline__ floatx4 splat4(float v) { floatx4 r; r[0]=v; r[1]=v; r[2]=v; r[3]=v; return r; }

#define N_WHH  (768*256)
#define N_WCAT (1024*256)
#define N_W1H  (256*256)
#define N_W2   (16*256)
#define N_TOT  (N_WHH + N_WCAT + N_W1H + N_W2)

#define GROW(r) (((((r)&7) ^ ((((r)>>3)&1)*5))) << 4)
#define A_SW(kk,q,row) ((((kk)<<6)+((q)<<4)) ^ GROW(row))

#define MF __builtin_amdgcn_mfma_f32_16x16x32_bf16

__global__ void prep_kernel(const float* __restrict__ w_hh, const float* __restrict__ w_ih,
                            const float* __restrict__ w1,  const float* __restrict__ w2,
                            unsigned short* __restrict__ Whh, unsigned short* __restrict__ Wcat,
                            unsigned short* __restrict__ W1h, unsigned short* __restrict__ W2b,
                            float* __restrict__ wzc) {
  int i = blockIdx.x * blockDim.x + threadIdx.x;
  if (i < N_WHH) {
    int n = i >> 8;
    Whh[i] = f2bf(w_hh[i] * (n < 512 ? LOG2E : TWO_LOG2E));
  } else if (i < N_WHH + N_WCAT) {
    int j = i - N_WHH; int n = j >> 8, k = j & 255;
    float v = 0.f;
    if (k < 208) {
      if (n < 768) v = w_ih[n * 209 + 1 + k] * (n < 512 ? LOG2E : TWO_LOG2E);
      else         v = w1[(n - 768) * 464 + 256 + k] * TWO_LOG2E;
    }
    Wcat[j] = f2bf(v);
  } else if (i < N_WHH + N_WCAT + N_W1H) {
    int j = i - N_WHH - N_WCAT; int n = j >> 8, k = j & 255;
    W1h[j] = f2bf(w1[n * 464 + k] * TWO_LOG2E);
  } else if (i < N_TOT) {
    int j = i - N_WHH - N_WCAT - N_W1H; int n = j >> 8, k = j & 255;
    W2b[j] = (n < 9) ? f2bf(w2[n * 256 + k]) : (unsigned short)0;
  } else if (i < N_TOT + 768) {
    int j = i - N_TOT;
    wzc[j] = w_ih[(size_t)j * 209] * (j < 512 ? LOG2E : TWO_LOG2E);
  }
}

__launch_bounds__(512, 1)
__global__ void const_kernel(const float* __restrict__ cc, const float* __restrict__ bb,
                             const float* __restrict__ mmat,
                             const float* __restrict__ b_ih, const float* __restrict__ b_hh,
                             const float* __restrict__ b1,
                             const unsigned short* __restrict__ Wcat,
                             float* __restrict__ CST, float* __restrict__ cnt,
                             float* __restrict__ cntmax) {
  __shared__ __align__(16) char smem[8192];
  const int tid = threadIdx.x;
  const int w = tid >> 6, l = tid & 63, q = l >> 4, li = l & 15;
  const int r0 = blockIdx.x << 4;

  {
    int row = tid >> 5, ch = tid & 31;
    float v[8];
#pragma unroll
    for (int j = 0; j < 8; j++) v[j] = 0.f;
    if (ch < 10) {
      const float* s = cc + (size_t)(r0 + row) * 80 + ch * 8;
#pragma unroll
      for (int j = 0; j < 8; j++) v[j] = s[j];
    } else if (ch < 18) {
      const float* s = bb + (size_t)(r0 + row) * 64 + (ch - 10) * 8;
#pragma unroll
      for (int j = 0; j < 8; j++) v[j] = s[j];
    } else if (ch < 26) {
      const float* s = mmat + (size_t)(r0 + row) * 64 + (ch - 18) * 8;
#pragma unroll
      for (int j = 0; j < 8; j++) v[j] = s[j];
    }
    short8 pk;
#pragma unroll
    for (int j = 0; j < 8; j++) pk[j] = (short)f2bf(v[j]);
    *(short8*)(smem + row * 512 + ((ch * 16) ^ GROW(row))) = pk;
  }
  __syncthreads();

  int col[8];
  floatx4 acc[8];
#pragma unroll
  for (int tt = 0; tt < 8; tt++) {
    col[tt] = (w * 8 + tt) * 16 + li;
    float bv;
    if (col[tt] < 512)      bv = LOG2E * (b_ih[col[tt]] + b_hh[col[tt]]);
    else if (col[tt] < 768) bv = TWO_LOG2E * b_ih[col[tt]];
    else                    bv = TWO_LOG2E * b1[col[tt] - 768];
    acc[tt] = splat4(bv);
  }
#pragma unroll
  for (int kk = 0; kk < 7; kk++) {
    short8 a = *(const short8*)(smem + li * 512 + A_SW(kk, q, li));
#pragma unroll
    for (int tt = 0; tt < 8; tt++) {
      short8 bf = *(const short8*)(Wcat + (size_t)col[tt] * 256 + kk * 32 + q * 8);
      acc[tt] = MF(a, bf, acc[tt], 0, 0, 0);
    }
  }
#pragma unroll
  for (int tt = 0; tt < 8; tt++)
#pragma unroll
    for (int r = 0; r < 4; r++)
      CST[(size_t)(r0 + q * 4 + r) * 1024 + col[tt]] = acc[tt][r];

  if (w == 0 && l < 16) {
    const float* bp = bb + (size_t)(r0 + l) * 64;
    const float* mp = mmat + (size_t)(r0 + l) * 64;
    float s = 0.f;
#pragma unroll 8
    for (int k2 = 0; k2 < 64; k2++) s += mp[k2] * (1.f - bp[k2]);
    cnt[r0 + l] = s;
    float mx = s;
#pragma unroll
    for (int off = 8; off; off >>= 1) mx = fmaxf(mx, __shfl_xor(mx, off, 16));
    if (l == 0) cntmax[blockIdx.x] = mx;
  }
}

// GRU scan v3 — transposed operands: A=weights (regs / L2-stream), B=h (one LDS read set).
// LDS: H dbuf @0 2x8KB, zb transposed @16384 4KB.
__launch_bounds__(512, 2)
__global__ void gru_kernel(const float* __restrict__ z, const float* __restrict__ b_hh,
                           const unsigned short* __restrict__ Whh,
                           const float* __restrict__ wzc,
                           const float* __restrict__ CST,
                           const float* __restrict__ cntmax,
                           char* __restrict__ hs) {
  __shared__ __align__(16) char smem[20480];
  const int tid = threadIdx.x;
  const int w = tid >> 6, l = tid & 63, q = l >> 4, li = l & 15;
  const int r0 = blockIdx.x << 4;
  const int nsteps = (int)(cntmax[blockIdx.x] + 0.5f);

  // zero h slot 0
  *(floatx4*)(smem + tid * 16) = splat4(0.f);
  // stage z transposed: zb[t*16+row]
  {
    float* zb = (float*)(smem + 16384);
    zb[tid] = z[(size_t)(r0 + (tid & 15)) * 64 + (tid >> 4)];
    int i1 = tid + 512;
    zb[i1] = z[(size_t)(r0 + (i1 & 15)) * 64 + (i1 >> 4)];
  }

  // weight A-frags in regs: tiles (g,nc): 0=(r,0) 1=(r,1) 2=(z,0) [3=(z,1) streamed] 4=(n,0) 5=(n,1)
  short8 wa0[8], wa1[8], wa2[8], wa4[8], wa5[8];
  {
    const unsigned short* p0 = Whh + (size_t)((w << 5) + li) * 256 + q * 8;
    const unsigned short* p1 = Whh + (size_t)((w << 5) + 16 + li) * 256 + q * 8;
    const unsigned short* p2 = Whh + (size_t)(256 + (w << 5) + li) * 256 + q * 8;
    const unsigned short* p4 = Whh + (size_t)(512 + (w << 5) + li) * 256 + q * 8;
    const unsigned short* p5 = Whh + (size_t)(512 + (w << 5) + 16 + li) * 256 + q * 8;
#pragma unroll
    for (int kk = 0; kk < 8; kk++) {
      wa0[kk] = *(const short8*)(p0 + kk * 32);
      wa1[kk] = *(const short8*)(p1 + kk * 32);
      wa2[kk] = *(const short8*)(p2 + kk * 32);
      wa4[kk] = *(const short8*)(p4 + kk * 32);
      wa5[kk] = *(const short8*)(p5 + kk * 32);
    }
  }

  // packed per-lane constants (transposed: batch=li, gatecols = base+4q+{0..3})
  const size_t crow = (size_t)(r0 + li) * 1024;
  unsigned crz[4][2], cn[2][2], bh[2][2], wz[6][2];
#pragma unroll
  for (int tt = 0; tt < 4; tt++) {
    int base = (tt >> 1) * 256 + (w << 5) + ((tt & 1) << 4) + (q << 2);
    floatx4 c = *(const floatx4*)(CST + crow + base);
    crz[tt][0] = cvt_pk(c[0], c[1]); crz[tt][1] = cvt_pk(c[2], c[3]);
  }
#pragma unroll
  for (int nc = 0; nc < 2; nc++) {
    int base = 512 + (w << 5) + (nc << 4) + (q << 2);
    floatx4 c = *(const floatx4*)(CST + crow + base);
    cn[nc][0] = cvt_pk(c[0], c[1]); cn[nc][1] = cvt_pk(c[2], c[3]);
    floatx4 b = *(const floatx4*)(b_hh + base);
    bh[nc][0] = cvt_pk(b[0] * TWO_LOG2E, b[1] * TWO_LOG2E);
    bh[nc][1] = cvt_pk(b[2] * TWO_LOG2E, b[3] * TWO_LOG2E);
  }
#pragma unroll
  for (int tt = 0; tt < 6; tt++) {
    int base = (tt >> 1) * 256 + (w << 5) + ((tt & 1) << 4) + (q << 2);
    floatx4 c = *(const floatx4*)(wzc + base);
    wz[tt][0] = cvt_pk(c[0], c[1]); wz[tt][1] = cvt_pk(c[2], c[3]);
  }

  unsigned hpk[2][2] = {{0u, 0u}, {0u, 0u}};   // packed bf16 h (lane's 8 cols)

  __syncthreads();
  char* hs_blk = hs + (size_t)blockIdx.x * 524288;

#pragma unroll 1
  for (int t = 0; t < nsteps; t++) {
    const char* hp = smem + ((t & 1) << 13);
    char* hc = smem + (((t + 1) & 1) << 13);

    // laundered pointer: force per-step L2-stream of tile 3 (z,nc=1) instead of reg hoist
    const unsigned short* w3p = Whh + (size_t)(256 + (w << 5) + 16 + li) * 256 + q * 8;
    asm("" : "+v"(w3p));

    floatx4 a0, a1, a2, a3, a4, a5;
    a0[0]=bfp_lo(crz[0][0]); a0[1]=bfp_hi(crz[0][0]); a0[2]=bfp_lo(crz[0][1]); a0[3]=bfp_hi(crz[0][1]);
    a1[0]=bfp_lo(crz[1][0]); a1[1]=bfp_hi(crz[1][0]); a1[2]=bfp_lo(crz[1][1]); a1[3]=bfp_hi(crz[1][1]);
    a2[0]=bfp_lo(crz[2][0]); a2[1]=bfp_hi(crz[2][0]); a2[2]=bfp_lo(crz[2][1]); a2[3]=bfp_hi(crz[2][1]);
    a3[0]=bfp_lo(crz[3][0]); a3[1]=bfp_hi(crz[3][0]); a3[2]=bfp_lo(crz[3][1]); a3[3]=bfp_hi(crz[3][1]);
    a4 = splat4(0.f); a5 = splat4(0.f);

#define LDH(kk) (*(const short8*)(hp + li * 512 + A_SW(kk, q, li)))
    short8 bA = LDH(0), bB = LDH(1);
    short8 w3A = *(const short8*)(w3p);
    short8 w3B = *(const short8*)(w3p + 32);

#define KSTEP(kk, bX, w3X, bY, w3Y)                                         \
    a0 = MF(wa0[kk], bX, a0, 0, 0, 0);                                      \
    a1 = MF(wa1[kk], bX, a1, 0, 0, 0);                                      \
    a2 = MF(wa2[kk], bX, a2, 0, 0, 0);                                      \
    a3 = MF(w3X,     bX, a3, 0, 0, 0);                                      \
    a4 = MF(wa4[kk], bX, a4, 0, 0, 0);                                      \
    a5 = MF(wa5[kk], bX, a5, 0, 0, 0);                                      \
    if ((kk) < 6) { bX = LDH((kk) + 2); w3X = *(const short8*)(w3p + ((kk) + 2) * 32); }

    KSTEP(0, bA, w3A, bB, w3B)
    KSTEP(1, bB, w3B, bA, w3A)
    KSTEP(2, bA, w3A, bB, w3B)
    KSTEP(3, bB, w3B, bA, w3A)
    KSTEP(4, bA, w3A, bB, w3B)
    KSTEP(5, bB, w3B, bA, w3A)
    KSTEP(6, bA, w3A, bB, w3B)
    KSTEP(7, bB, w3B, bA, w3A)
#undef KSTEP
#undef LDH

    float zp = -1.f;
    if (t) zp = ((const float*)(smem + 16384))[(t - 1) * 16 + li];

#define GATE(nc, pr, aR, aZ, aN)                                                    \
    {                                                                               \
      float rlo = sigm_fast(fmaf(zp, bfp_lo(wz[0 + nc][pr]), aR[2 * pr]));          \
      float rhi = sigm_fast(fmaf(zp, bfp_hi(wz[0 + nc][pr]), aR[2 * pr + 1]));      \
      float zlo = sigm_fast(fmaf(zp, bfp_lo(wz[2 + nc][pr]), aZ[2 * pr]));          \
      float zhi = sigm_fast(fmaf(zp, bfp_hi(wz[2 + nc][pr]), aZ[2 * pr + 1]));      \
      float gnlo = fmaf(zp, bfp_lo(wz[4 + nc][pr]), bfp_lo(cn[nc][pr]));            \
      float gnhi = fmaf(zp, bfp_hi(wz[4 + nc][pr]), bfp_hi(cn[nc][pr]));            \
      float nlo = tanh_fast(fmaf(rlo, aN[2 * pr] + bfp_lo(bh[nc][pr]), gnlo));      \
      float nhi = tanh_fast(fmaf(rhi, aN[2 * pr + 1] + bfp_hi(bh[nc][pr]), gnhi));  \
      unsigned hop = hpk[nc][pr];                                                   \
      float hlo = fmaf(zlo, bfp_lo(hop) - nlo, nlo);                                \
      float hhi = fmaf(zhi, bfp_hi(hop) - nhi, nhi);                                \
      unsigned np = cvt_pk(hlo, hhi);                                               \
      hpk[nc][pr] = np;                                                             \
      *(unsigned*)(hc + li * 512 +                                                  \
        (((w << 6) + ((nc) << 5) + (q << 3) + ((pr) << 2)) ^ GROW(li))) = np;       \
    }

    GATE(0, 0, a0, a2, a4)
    GATE(0, 1, a0, a2, a4)
    GATE(1, 0, a1, a3, a5)
    GATE(1, 1, a1, a3, a5)
#undef GATE

    __syncthreads();
    *(short8*)(hs_blk + (size_t)t * 8192 + tid * 16) = *(const short8*)(hc + tid * 16);
  }
}

// MLP + GMM. Grid 1024 = tg-outer (tg in {0..3}) x 256 rowgroups; t = tg + 4s.
// LDS: A dbuf @0 2x8KB, U dbuf @16384 2x8KB, P @32768 1088B, zb @33856 1KB
__launch_bounds__(512, 2)
__global__ void mlp_kernel(const float* __restrict__ z, const float* __restrict__ b2,
                           const float* __restrict__ cnt, const float* __restrict__ cntmax,
                           const unsigned short* __restrict__ W1h,
                           const unsigned short* __restrict__ W2b,
                           const float* __restrict__ CST, const char* __restrict__ hs,
                           float* __restrict__ out) {
  __shared__ __align__(16) char smem[34880];
  const int tid = threadIdx.x;
  const int w = tid >> 6, l = tid & 63, q = l >> 4, li = l & 15;
  const int tg = blockIdx.x >> 8, rg = blockIdx.x & 255;
  const int r0 = rg << 4;

  const int nsteps = (int)(cntmax[rg] + 0.5f);
  const int count = (nsteps - tg + 3) >> 2;
  if (count <= 0) return;
  const char* img = hs + (size_t)rg * 524288;

  // stage z tile transposed: zb[s*16+row] = z[row][tg+4s]
  if (tid < 256) {
    int s = tid >> 4, row = tid & 15;
    ((float*)(smem + 33856))[tid] = z[(size_t)(r0 + row) * 64 + tg + 4 * s];
  }

  int col[2];
#pragma unroll
  for (int nc = 0; nc < 2; nc++) col[nc] = (w << 5) + (nc << 4) + li;

  short8 w1reg[2][8];
#pragma unroll
  for (int nc = 0; nc < 2; nc++)
#pragma unroll
    for (int kk = 0; kk < 8; kk++)
      w1reg[nc][kk] = *(const short8*)(W1h + (size_t)col[nc] * 256 + kk * 32 + q * 8);

  float cst1[2][4];
#pragma unroll
  for (int nc = 0; nc < 2; nc++)
#pragma unroll
    for (int r = 0; r < 4; r++)
      cst1[nc][r] = CST[(size_t)(r0 + q * 4 + r) * 1024 + 768 + col[nc]];

  float b2v = (li < 9) ? b2[li] : 0.f;
  float cl = (l < 16) ? cnt[r0 + l] : 0.f;
  float lacc = 0.f;

  // stage A slot 0 (t = tg)
  {
    short8 v = *(const short8*)(img + (size_t)tg * 8192 + tid * 16);
    *(short8*)(smem + tid * 16) = v;
  }
  __syncthreads();

#pragma unroll 1
  for (int s = 0; s < count; s++) {
    int t = tg + 4 * s;
    // T14 split: issue next-image load now, ds_write after compute
    short8 pf;
    bool do_pf = (s + 1 < count);
    if (do_pf) pf = *(const short8*)(img + (size_t)(t + 4) * 8192 + tid * 16);

    floatx4 acc[2];
    acc[0] = splat4(0.f); acc[1] = splat4(0.f);
    const char* As = smem + (s & 1) * 8192;
#pragma unroll
    for (int kk = 0; kk < 8; kk++) {
      short8 a = *(const short8*)(As + li * 512 + A_SW(kk, q, li));
      acc[0] = MF(a, w1reg[0][kk], acc[0], 0, 0, 0);
      acc[1] = MF(a, w1reg[1][kk], acc[1], 0, 0, 0);
    }
    char* Us = smem + 16384 + (s & 1) * 8192;
#pragma unroll
    for (int nc = 0; nc < 2; nc++)
#pragma unroll
      for (int r = 0; r < 4; r++) {
        float uv = tanh_fast(acc[nc][r] + cst1[nc][r]);
        int rw = (q << 2) + r;
        int colb = col[nc] << 1;
        *(unsigned short*)(Us + rw * 512 + (colb ^ GROW(rw))) = f2bf(uv);
      }
    if (do_pf) *(short8*)(smem + ((s + 1) & 1) * 8192 + tid * 16) = pf;
    __syncthreads();

    if (w == (s & 7)) {   // duty wave: w2 GEMM + GMM epilogue
      floatx4 pacc = splat4(b2v);
#pragma unroll
      for (int kk = 0; kk < 8; kk++) {
        short8 au = *(const short8*)(Us + li * 512 + A_SW(kk, q, li));
        short8 bw = *(const short8*)(W2b + (size_t)li * 256 + kk * 32 + q * 8);
        pacc = MF(au, bw, pacc, 0, 0, 0);
      }
      float* Pw = (float*)(smem + 32768);
#pragma unroll
      for (int r = 0; r < 4; r++) Pw[((q << 2) + r) * 17 + li] = pacc[r];
      if (l < 16) {
        const float* pr = Pw + l * 17;
        float zt = ((const float*)(smem + 33856))[s * 16 + l];
        float aj[3], lg[3];
#pragma unroll
        for (int j = 0; j < 3; j++) {
          float lgt = pr[j];
          float mean = pr[3 + j];
          float ls = pr[6 + j];
          float d = (zt - mean) * __expf(-ls);
          lg[j] = lgt;
          aj[j] = lgt - ls - 0.9189385332f - 0.5f * d * d;
        }
        float mx = fmaxf(aj[0], fmaxf(aj[1], aj[2]));
        float ln_n = mx + __logf(__expf(aj[0] - mx) + __expf(aj[1] - mx) + __expf(aj[2] - mx));
        float mg = fmaxf(lg[0], fmaxf(lg[1], lg[2]));
        float ln_d = mg + __logf(__expf(lg[0] - mg) + __expf(lg[1] - mg) + __expf(lg[2] - mg));
        if ((float)t + 0.5f < cl) lacc += (ln_n - ln_d);
      }
    }
  }

  __syncthreads();
  if (l < 16) ((float*)(smem + 32768))[w * 16 + l] = lacc;
  __syncthreads();
  if (w == 0 && l < 16) {
    const float* F = (const float*)(smem + 32768);
    float s = 0.f;
#pragma unroll
    for (int ww = 0; ww < 8; ww++) s += F[ww * 16 + l];
    atomicAdd(&out[r0 + l], s);
  }
}

extern "C" void kernel_launch(void* const* d_in, const int* in_sizes, int n_in,
                              void* d_out, int out_size, void* d_ws, size_t ws_size,
                              hipStream_t stream) {
  const float* z    = (const float*)d_in[0];
  const float* c    = (const float*)d_in[1];
  const float* b    = (const float*)d_in[2];
  const float* m    = (const float*)d_in[3];
  const float* w_ih = (const float*)d_in[4];
  const float* w_hh = (const float*)d_in[5];
  const float* b_ih = (const float*)d_in[6];
  const float* b_hh = (const float*)d_in[7];
  const float* w1   = (const float*)d_in[8];
  const float* b1   = (const float*)d_in[9];
  const float* w2   = (const float*)d_in[10];
  const float* b2   = (const float*)d_in[11];

  char* ws = (char*)d_ws;
  unsigned short* Whh  = (unsigned short*)(ws);
  unsigned short* Wcat = (unsigned short*)(ws + 393216);
  unsigned short* W1h  = (unsigned short*)(ws + 917504);
  unsigned short* W2b  = (unsigned short*)(ws + 1048576);
  float*          CST  = (float*)(ws + 1056768);
  float*          cnt  = (float*)(ws + 17833984);
  float*          cmax = (float*)(ws + 17850368);
  float*          wzc  = (float*)(ws + 17851392);
  char*           hs   = ws + 17916928;

  hipMemsetAsync(d_out, 0, (size_t)out_size * sizeof(float), stream);
  hipLaunchKernelGGL(prep_kernel, dim3((N_TOT + 768) / 256), dim3(256), 0, stream,
                     w_hh, w_ih, w1, w2, Whh, Wcat, W1h, W2b, wzc);
  hipLaunchKernelGGL(const_kernel, dim3(256), dim3(512), 0, stream,
                     c, b, m, b_ih, b_hh, b1, Wcat, CST, cnt, cmax);
  hipLaunchKernelGGL(gru_kernel, dim3(256), dim3(512), 0, stream,
                     z, b_hh, Whh, wzc, CST, cmax, hs);
  hipLaunchKernelGGL(mlp_kernel, dim3(1024), dim3(512), 0, stream,
                     z, b2, cnt, cmax, W1h, W2b, CST, hs, (float*)d_out);
}

// Round 6
// 310.549 us; speedup vs baseline: 1.0094x; 1.0094x over previous
//
#include <hip/hip_runtime.h>

typedef __attribute__((ext_vector_type(8))) short short8;
typedef __attribute__((ext_vector_type(4))) float floatx4;

#define LOG2E     1.4426950408889634f
#define TWO_LOG2E 2.8853900817779268f

__device__ __forceinline__ unsigned short f2bf(float x) {
  union { float f; unsigned u; } v; v.f = x;
  unsigned r = v.u + 0x7fffu + ((v.u >> 16) & 1u);
  return (unsigned short)(r >> 16);
}
__device__ __forceinline__ unsigned cvt_pk(float lo, float hi) {
  unsigned r;
  asm("v_cvt_pk_bf16_f32 %0, %1, %2" : "=v"(r) : "v"(lo), "v"(hi));
  return r;
}
__device__ __forceinline__ float bfp_lo(unsigned p) { return __builtin_bit_cast(float, p << 16); }
__device__ __forceinline__ float bfp_hi(unsigned p) { return __builtin_bit_cast(float, p & 0xffff0000u); }
// s pre-scaled by log2e: sigmoid(x) = 1/(1+2^-s)
__device__ __forceinline__ float sigm_fast(float s) {
  return __builtin_amdgcn_rcpf(1.f + __builtin_amdgcn_exp2f(-s));
}
// y pre-scaled by 2*log2e: tanh(x) = 1 - 2/(1+2^y)
__device__ __forceinline__ float tanh_fast(float y) {
  return fmaf(-2.f, __builtin_amdgcn_rcpf(1.f + __builtin_amdgcn_exp2f(y)), 1.f);
}
__device__ __forceinline__ floatx4 splat4(float v) { floatx4 r; r[0]=v; r[1]=v; r[2]=v; r[3]=v; return r; }

#define N_WHH  (768*256)
#define N_WCAT (1024*256)
#define N_W1H  (256*256)
#define N_W2   (16*256)
#define N_TOT  (N_WHH + N_WCAT + N_W1H + N_W2)

#define GROW(r) (((((r)&7) ^ ((((r)>>3)&1)*5))) << 4)
#define A_SW(kk,q,row) ((((kk)<<6)+((q)<<4)) ^ GROW(row))

#define MF __builtin_amdgcn_mfma_f32_16x16x32_bf16

__global__ void prep_kernel(const float* __restrict__ w_hh, const float* __restrict__ w_ih,
                            const float* __restrict__ w1,  const float* __restrict__ w2,
                            unsigned short* __restrict__ Whh, unsigned short* __restrict__ Wcat,
                            unsigned short* __restrict__ W1h, unsigned short* __restrict__ W2b,
                            float* __restrict__ wzc) {
  int i = blockIdx.x * blockDim.x + threadIdx.x;
  if (i < N_WHH) {
    int n = i >> 8;
    Whh[i] = f2bf(w_hh[i] * (n < 512 ? LOG2E : TWO_LOG2E));
  } else if (i < N_WHH + N_WCAT) {
    int j = i - N_WHH; int n = j >> 8, k = j & 255;
    float v = 0.f;
    if (k < 208) {
      if (n < 768) v = w_ih[n * 209 + 1 + k] * (n < 512 ? LOG2E : TWO_LOG2E);
      else         v = w1[(n - 768) * 464 + 256 + k] * TWO_LOG2E;
    }
    Wcat[j] = f2bf(v);
  } else if (i < N_WHH + N_WCAT + N_W1H) {
    int j = i - N_WHH - N_WCAT; int n = j >> 8, k = j & 255;
    W1h[j] = f2bf(w1[n * 464 + k] * TWO_LOG2E);
  } else if (i < N_TOT) {
    int j = i - N_WHH - N_WCAT - N_W1H; int n = j >> 8, k = j & 255;
    W2b[j] = (n < 9) ? f2bf(w2[n * 256 + k]) : (unsigned short)0;
  } else if (i < N_TOT + 768) {
    int j = i - N_TOT;
    wzc[j] = w_ih[(size_t)j * 209] * (j < 512 ? LOG2E : TWO_LOG2E);
  }
}

__launch_bounds__(512, 1)
__global__ void const_kernel(const float* __restrict__ cc, const float* __restrict__ bb,
                             const float* __restrict__ mmat,
                             const float* __restrict__ b_ih, const float* __restrict__ b_hh,
                             const float* __restrict__ b1,
                             const unsigned short* __restrict__ Wcat,
                             float* __restrict__ CST, float* __restrict__ cnt,
                             float* __restrict__ cntmax) {
  __shared__ __align__(16) char smem[8192];
  const int tid = threadIdx.x;
  const int w = tid >> 6, l = tid & 63, q = l >> 4, li = l & 15;
  const int r0 = blockIdx.x << 4;

  {
    int row = tid >> 5, ch = tid & 31;
    float v[8];
#pragma unroll
    for (int j = 0; j < 8; j++) v[j] = 0.f;
    if (ch < 10) {
      const float* s = cc + (size_t)(r0 + row) * 80 + ch * 8;
#pragma unroll
      for (int j = 0; j < 8; j++) v[j] = s[j];
    } else if (ch < 18) {
      const float* s = bb + (size_t)(r0 + row) * 64 + (ch - 10) * 8;
#pragma unroll
      for (int j = 0; j < 8; j++) v[j] = s[j];
    } else if (ch < 26) {
      const float* s = mmat + (size_t)(r0 + row) * 64 + (ch - 18) * 8;
#pragma unroll
      for (int j = 0; j < 8; j++) v[j] = s[j];
    }
    short8 pk;
#pragma unroll
    for (int j = 0; j < 8; j++) pk[j] = (short)f2bf(v[j]);
    *(short8*)(smem + row * 512 + ((ch * 16) ^ GROW(row))) = pk;
  }
  __syncthreads();

  int col[8];
  floatx4 acc[8];
#pragma unroll
  for (int tt = 0; tt < 8; tt++) {
    col[tt] = (w * 8 + tt) * 16 + li;
    float bv;
    if (col[tt] < 512)      bv = LOG2E * (b_ih[col[tt]] + b_hh[col[tt]]);
    else if (col[tt] < 768) bv = TWO_LOG2E * b_ih[col[tt]];
    else                    bv = TWO_LOG2E * b1[col[tt] - 768];
    acc[tt] = splat4(bv);
  }
#pragma unroll
  for (int kk = 0; kk < 7; kk++) {
    short8 a = *(const short8*)(smem + li * 512 + A_SW(kk, q, li));
#pragma unroll
    for (int tt = 0; tt < 8; tt++) {
      short8 bf = *(const short8*)(Wcat + (size_t)col[tt] * 256 + kk * 32 + q * 8);
      acc[tt] = MF(a, bf, acc[tt], 0, 0, 0);
    }
  }
#pragma unroll
  for (int tt = 0; tt < 8; tt++)
#pragma unroll
    for (int r = 0; r < 4; r++)
      CST[(size_t)(r0 + q * 4 + r) * 1024 + col[tt]] = acc[tt][r];

  if (w == 0 && l < 16) {
    const float* bp = bb + (size_t)(r0 + l) * 64;
    const float* mp = mmat + (size_t)(r0 + l) * 64;
    float s = 0.f;
#pragma unroll 8
    for (int k2 = 0; k2 < 64; k2++) s += mp[k2] * (1.f - bp[k2]);
    cnt[r0 + l] = s;
    float mx = s;
#pragma unroll
    for (int off = 8; off; off >>= 1) mx = fmaxf(mx, __shfl_xor(mx, off, 16));
    if (l == 0) cntmax[blockIdx.x] = mx;
  }
}

// GRU scan v3 — transposed operands: A=weights (regs / L2-stream), B=h (one LDS read set).
// LDS: H dbuf @0 2x8KB, zb transposed @16384 4KB.
// launch_bounds(512,1): the 5 register-resident weight tiles need ~160 VGPR;
// (512,2)'s 128-cap spilled them to scratch (round-5 regression: 79->176us).
__launch_bounds__(512, 1)
__global__ void gru_kernel(const float* __restrict__ z, const float* __restrict__ b_hh,
                           const unsigned short* __restrict__ Whh,
                           const float* __restrict__ wzc,
                           const float* __restrict__ CST,
                           const float* __restrict__ cntmax,
                           char* __restrict__ hs) {
  __shared__ __align__(16) char smem[20480];
  const int tid = threadIdx.x;
  const int w = tid >> 6, l = tid & 63, q = l >> 4, li = l & 15;
  const int r0 = blockIdx.x << 4;
  const int nsteps = (int)(cntmax[blockIdx.x] + 0.5f);

  // zero h slot 0
  *(floatx4*)(smem + tid * 16) = splat4(0.f);
  // stage z transposed: zb[t*16+row]
  {
    float* zb = (float*)(smem + 16384);
    zb[tid] = z[(size_t)(r0 + (tid & 15)) * 64 + (tid >> 4)];
    int i1 = tid + 512;
    zb[i1] = z[(size_t)(r0 + (i1 & 15)) * 64 + (i1 >> 4)];
  }

  // weight A-frags in regs: tiles (g,nc): 0=(r,0) 1=(r,1) 2=(z,0) [3=(z,1) streamed] 4=(n,0) 5=(n,1)
  short8 wa0[8], wa1[8], wa2[8], wa4[8], wa5[8];
  {
    const unsigned short* p0 = Whh + (size_t)((w << 5) + li) * 256 + q * 8;
    const unsigned short* p1 = Whh + (size_t)((w << 5) + 16 + li) * 256 + q * 8;
    const unsigned short* p2 = Whh + (size_t)(256 + (w << 5) + li) * 256 + q * 8;
    const unsigned short* p4 = Whh + (size_t)(512 + (w << 5) + li) * 256 + q * 8;
    const unsigned short* p5 = Whh + (size_t)(512 + (w << 5) + 16 + li) * 256 + q * 8;
#pragma unroll
    for (int kk = 0; kk < 8; kk++) {
      wa0[kk] = *(const short8*)(p0 + kk * 32);
      wa1[kk] = *(const short8*)(p1 + kk * 32);
      wa2[kk] = *(const short8*)(p2 + kk * 32);
      wa4[kk] = *(const short8*)(p4 + kk * 32);
      wa5[kk] = *(const short8*)(p5 + kk * 32);
    }
  }

  // packed per-lane constants (transposed: batch=li, gatecols = base+4q+{0..3})
  const size_t crow = (size_t)(r0 + li) * 1024;
  unsigned crz[4][2], cn[2][2], bh[2][2], wz[6][2];
#pragma unroll
  for (int tt = 0; tt < 4; tt++) {
    int base = (tt >> 1) * 256 + (w << 5) + ((tt & 1) << 4) + (q << 2);
    floatx4 c = *(const floatx4*)(CST + crow + base);
    crz[tt][0] = cvt_pk(c[0], c[1]); crz[tt][1] = cvt_pk(c[2], c[3]);
  }
#pragma unroll
  for (int nc = 0; nc < 2; nc++) {
    int base = 512 + (w << 5) + (nc << 4) + (q << 2);
    floatx4 c = *(const floatx4*)(CST + crow + base);
    cn[nc][0] = cvt_pk(c[0], c[1]); cn[nc][1] = cvt_pk(c[2], c[3]);
    floatx4 b = *(const floatx4*)(b_hh + base);
    bh[nc][0] = cvt_pk(b[0] * TWO_LOG2E, b[1] * TWO_LOG2E);
    bh[nc][1] = cvt_pk(b[2] * TWO_LOG2E, b[3] * TWO_LOG2E);
  }
#pragma unroll
  for (int tt = 0; tt < 6; tt++) {
    int base = (tt >> 1) * 256 + (w << 5) + ((tt & 1) << 4) + (q << 2);
    floatx4 c = *(const floatx4*)(wzc + base);
    wz[tt][0] = cvt_pk(c[0], c[1]); wz[tt][1] = cvt_pk(c[2], c[3]);
  }

  unsigned hpk[2][2] = {{0u, 0u}, {0u, 0u}};   // packed bf16 h (lane's 8 cols)

  __syncthreads();
  char* hs_blk = hs + (size_t)blockIdx.x * 524288;

#pragma unroll 1
  for (int t = 0; t < nsteps; t++) {
    const char* hp = smem + ((t & 1) << 13);
    char* hc = smem + (((t + 1) & 1) << 13);

    // laundered pointer: force per-step L2-stream of tile 3 (z,nc=1) instead of reg hoist
    const unsigned short* w3p = Whh + (size_t)(256 + (w << 5) + 16 + li) * 256 + q * 8;
    asm("" : "+v"(w3p));

    floatx4 a0, a1, a2, a3, a4, a5;
    a0[0]=bfp_lo(crz[0][0]); a0[1]=bfp_hi(crz[0][0]); a0[2]=bfp_lo(crz[0][1]); a0[3]=bfp_hi(crz[0][1]);
    a1[0]=bfp_lo(crz[1][0]); a1[1]=bfp_hi(crz[1][0]); a1[2]=bfp_lo(crz[1][1]); a1[3]=bfp_hi(crz[1][1]);
    a2[0]=bfp_lo(crz[2][0]); a2[1]=bfp_hi(crz[2][0]); a2[2]=bfp_lo(crz[2][1]); a2[3]=bfp_hi(crz[2][1]);
    a3[0]=bfp_lo(crz[3][0]); a3[1]=bfp_hi(crz[3][0]); a3[2]=bfp_lo(crz[3][1]); a3[3]=bfp_hi(crz[3][1]);
    a4 = splat4(0.f); a5 = splat4(0.f);

#define LDH(kk) (*(const short8*)(hp + li * 512 + A_SW(kk, q, li)))
    short8 bA = LDH(0), bB = LDH(1);
    short8 w3A = *(const short8*)(w3p);
    short8 w3B = *(const short8*)(w3p + 32);

#define KSTEP(kk, bX, w3X, bY, w3Y)                                         \
    a0 = MF(wa0[kk], bX, a0, 0, 0, 0);                                      \
    a1 = MF(wa1[kk], bX, a1, 0, 0, 0);                                      \
    a2 = MF(wa2[kk], bX, a2, 0, 0, 0);                                      \
    a3 = MF(w3X,     bX, a3, 0, 0, 0);                                      \
    a4 = MF(wa4[kk], bX, a4, 0, 0, 0);                                      \
    a5 = MF(wa5[kk], bX, a5, 0, 0, 0);                                      \
    if ((kk) < 6) { bX = LDH((kk) + 2); w3X = *(const short8*)(w3p + ((kk) + 2) * 32); }

    KSTEP(0, bA, w3A, bB, w3B)
    KSTEP(1, bB, w3B, bA, w3A)
    KSTEP(2, bA, w3A, bB, w3B)
    KSTEP(3, bB, w3B, bA, w3A)
    KSTEP(4, bA, w3A, bB, w3B)
    KSTEP(5, bB, w3B, bA, w3A)
    KSTEP(6, bA, w3A, bB, w3B)
    KSTEP(7, bB, w3B, bA, w3A)
#undef KSTEP
#undef LDH

    float zp = -1.f;
    if (t) zp = ((const float*)(smem + 16384))[(t - 1) * 16 + li];

#define GATE(nc, pr, aR, aZ, aN)                                                    \
    {                                                                               \
      float rlo = sigm_fast(fmaf(zp, bfp_lo(wz[0 + nc][pr]), aR[2 * pr]));          \
      float rhi = sigm_fast(fmaf(zp, bfp_hi(wz[0 + nc][pr]), aR[2 * pr + 1]));      \
      float zlo = sigm_fast(fmaf(zp, bfp_lo(wz[2 + nc][pr]), aZ[2 * pr]));          \
      float zhi = sigm_fast(fmaf(zp, bfp_hi(wz[2 + nc][pr]), aZ[2 * pr + 1]));      \
      float gnlo = fmaf(zp, bfp_lo(wz[4 + nc][pr]), bfp_lo(cn[nc][pr]));            \
      float gnhi = fmaf(zp, bfp_hi(wz[4 + nc][pr]), bfp_hi(cn[nc][pr]));            \
      float nlo = tanh_fast(fmaf(rlo, aN[2 * pr] + bfp_lo(bh[nc][pr]), gnlo));      \
      float nhi = tanh_fast(fmaf(rhi, aN[2 * pr + 1] + bfp_hi(bh[nc][pr]), gnhi));  \
      unsigned hop = hpk[nc][pr];                                                   \
      float hlo = fmaf(zlo, bfp_lo(hop) - nlo, nlo);                                \
      float hhi = fmaf(zhi, bfp_hi(hop) - nhi, nhi);                                \
      unsigned np = cvt_pk(hlo, hhi);                                               \
      hpk[nc][pr] = np;                                                             \
      *(unsigned*)(hc + li * 512 +                                                  \
        (((w << 6) + ((nc) << 5) + (q << 3) + ((pr) << 2)) ^ GROW(li))) = np;       \
    }

    GATE(0, 0, a0, a2, a4)
    GATE(0, 1, a0, a2, a4)
    GATE(1, 0, a1, a3, a5)
    GATE(1, 1, a1, a3, a5)
#undef GATE

    __syncthreads();
    *(short8*)(hs_blk + (size_t)t * 8192 + tid * 16) = *(const short8*)(hc + tid * 16);
  }
}

// MLP + GMM. Grid 1024 = tg-outer (tg in {0..3}) x 256 rowgroups; t = tg + 4s.
// LDS: A dbuf @0 2x8KB, U dbuf @16384 2x8KB, P @32768 1088B, zb @33856 1KB
__launch_bounds__(512, 2)
__global__ void mlp_kernel(const float* __restrict__ z, const float* __restrict__ b2,
                           const float* __restrict__ cnt, const float* __restrict__ cntmax,
                           const unsigned short* __restrict__ W1h,
                           const unsigned short* __restrict__ W2b,
                           const float* __restrict__ CST, const char* __restrict__ hs,
                           float* __restrict__ out) {
  __shared__ __align__(16) char smem[34880];
  const int tid = threadIdx.x;
  const int w = tid >> 6, l = tid & 63, q = l >> 4, li = l & 15;
  const int tg = blockIdx.x >> 8, rg = blockIdx.x & 255;
  const int r0 = rg << 4;

  const int nsteps = (int)(cntmax[rg] + 0.5f);
  const int count = (nsteps - tg + 3) >> 2;
  if (count <= 0) return;
  const char* img = hs + (size_t)rg * 524288;

  // stage z tile transposed: zb[s*16+row] = z[row][tg+4s]
  if (tid < 256) {
    int s = tid >> 4, row = tid & 15;
    ((float*)(smem + 33856))[tid] = z[(size_t)(r0 + row) * 64 + tg + 4 * s];
  }

  int col[2];
#pragma unroll
  for (int nc = 0; nc < 2; nc++) col[nc] = (w << 5) + (nc << 4) + li;

  short8 w1reg[2][8];
#pragma unroll
  for (int nc = 0; nc < 2; nc++)
#pragma unroll
    for (int kk = 0; kk < 8; kk++)
      w1reg[nc][kk] = *(const short8*)(W1h + (size_t)col[nc] * 256 + kk * 32 + q * 8);

  float cst1[2][4];
#pragma unroll
  for (int nc = 0; nc < 2; nc++)
#pragma unroll
    for (int r = 0; r < 4; r++)
      cst1[nc][r] = CST[(size_t)(r0 + q * 4 + r) * 1024 + 768 + col[nc]];

  float b2v = (li < 9) ? b2[li] : 0.f;
  float cl = (l < 16) ? cnt[r0 + l] : 0.f;
  float lacc = 0.f;

  // stage A slot 0 (t = tg)
  {
    short8 v = *(const short8*)(img + (size_t)tg * 8192 + tid * 16);
    *(short8*)(smem + tid * 16) = v;
  }
  __syncthreads();

#pragma unroll 1
  for (int s = 0; s < count; s++) {
    int t = tg + 4 * s;
    // T14 split: issue next-image load now, ds_write after compute
    short8 pf;
    bool do_pf = (s + 1 < count);
    if (do_pf) pf = *(const short8*)(img + (size_t)(t + 4) * 8192 + tid * 16);

    floatx4 acc[2];
    acc[0] = splat4(0.f); acc[1] = splat4(0.f);
    const char* As = smem + (s & 1) * 8192;
#pragma unroll
    for (int kk = 0; kk < 8; kk++) {
      short8 a = *(const short8*)(As + li * 512 + A_SW(kk, q, li));
      acc[0] = MF(a, w1reg[0][kk], acc[0], 0, 0, 0);
      acc[1] = MF(a, w1reg[1][kk], acc[1], 0, 0, 0);
    }
    char* Us = smem + 16384 + (s & 1) * 8192;
#pragma unroll
    for (int nc = 0; nc < 2; nc++)
#pragma unroll
      for (int r = 0; r < 4; r++) {
        float uv = tanh_fast(acc[nc][r] + cst1[nc][r]);
        int rw = (q << 2) + r;
        int colb = col[nc] << 1;
        *(unsigned short*)(Us + rw * 512 + (colb ^ GROW(rw))) = f2bf(uv);
      }
    if (do_pf) *(short8*)(smem + ((s + 1) & 1) * 8192 + tid * 16) = pf;
    __syncthreads();

    if (w == (s & 7)) {   // duty wave: w2 GEMM + GMM epilogue
      floatx4 pacc = splat4(b2v);
#pragma unroll
      for (int kk = 0; kk < 8; kk++) {
        short8 au = *(const short8*)(Us + li * 512 + A_SW(kk, q, li));
        short8 bw = *(const short8*)(W2b + (size_t)li * 256 + kk * 32 + q * 8);
        pacc = MF(au, bw, pacc, 0, 0, 0);
      }
      float* Pw = (float*)(smem + 32768);
#pragma unroll
      for (int r = 0; r < 4; r++) Pw[((q << 2) + r) * 17 + li] = pacc[r];
      if (l < 16) {
        const float* pr = Pw + l * 17;
        float zt = ((const float*)(smem + 33856))[s * 16 + l];
        float aj[3], lg[3];
#pragma unroll
        for (int j = 0; j < 3; j++) {
          float lgt = pr[j];
          float mean = pr[3 + j];
          float ls = pr[6 + j];
          float d = (zt - mean) * __expf(-ls);
          lg[j] = lgt;
          aj[j] = lgt - ls - 0.9189385332f - 0.5f * d * d;
        }
        float mx = fmaxf(aj[0], fmaxf(aj[1], aj[2]));
        float ln_n = mx + __logf(__expf(aj[0] - mx) + __expf(aj[1] - mx) + __expf(aj[2] - mx));
        float mg = fmaxf(lg[0], fmaxf(lg[1], lg[2]));
        float ln_d = mg + __logf(__expf(lg[0] - mg) + __expf(lg[1] - mg) + __expf(lg[2] - mg));
        if ((float)t + 0.5f < cl) lacc += (ln_n - ln_d);
      }
    }
  }

  __syncthreads();
  if (l < 16) ((float*)(smem + 32768))[w * 16 + l] = lacc;
  __syncthreads();
  if (w == 0 && l < 16) {
    const float* F = (const float*)(smem + 32768);
    float s = 0.f;
#pragma unroll
    for (int ww = 0; ww < 8; ww++) s += F[ww * 16 + l];
    atomicAdd(&out[r0 + l], s);
  }
}

extern "C" void kernel_launch(void* const* d_in, const int* in_sizes, int n_in,
                              void* d_out, int out_size, void* d_ws, size_t ws_size,
                              hipStream_t stream) {
  const float* z    = (const float*)d_in[0];
  const float* c    = (const float*)d_in[1];
  const float* b    = (const float*)d_in[2];
  const float* m    = (const float*)d_in[3];
  const float* w_ih = (const float*)d_in[4];
  const float* w_hh = (const float*)d_in[5];
  const float* b_ih = (const float*)d_in[6];
  const float* b_hh = (const float*)d_in[7];
  const float* w1   = (const float*)d_in[8];
  const float* b1   = (const float*)d_in[9];
  const float* w2   = (const float*)d_in[10];
  const float* b2   = (const float*)d_in[11];

  char* ws = (char*)d_ws;
  unsigned short* Whh  = (unsigned short*)(ws);
  unsigned short* Wcat = (unsigned short*)(ws + 393216);
  unsigned short* W1h  = (unsigned short*)(ws + 917504);
  unsigned short* W2b  = (unsigned short*)(ws + 1048576);
  float*          CST  = (float*)(ws + 1056768);
  float*          cnt  = (float*)(ws + 17833984);
  float*          cmax = (float*)(ws + 17850368);
  float*          wzc  = (float*)(ws + 17851392);
  char*           hs   = ws + 17916928;

  hipMemsetAsync(d_out, 0, (size_t)out_size * sizeof(float), stream);
  hipLaunchKernelGGL(prep_kernel, dim3((N_TOT + 768) / 256), dim3(256), 0, stream,
                     w_hh, w_ih, w1, w2, Whh, Wcat, W1h, W2b, wzc);
  hipLaunchKernelGGL(const_kernel, dim3(256), dim3(512), 0, stream,
                     c, b, m, b_ih, b_hh, b1, Wcat, CST, cnt, cmax);
  hipLaunchKernelGGL(gru_kernel, dim3(256), dim3(512), 0, stream,
                     z, b_hh, Whh, wzc, CST, cmax, hs);
  hipLaunchKernelGGL(mlp_kernel, dim3(1024), dim3(512), 0, stream,
                     z, b2, cnt, cmax, W1h, W2b, CST, hs, (float*)d_out);
}

// Round 7
// 219.015 us; speedup vs baseline: 1.4313x; 1.4179x over previous
//
#include <hip/hip_runtime.h>

typedef __attribute__((ext_vector_type(8))) short short8;
typedef __attribute__((ext_vector_type(4))) float floatx4;
typedef __attribute__((ext_vector_type(4))) unsigned int uint4v;

#define LOG2E     1.4426950408889634f
#define TWO_LOG2E 2.8853900817779268f

__device__ __forceinline__ unsigned short f2bf(float x) {
  union { float f; unsigned u; } v; v.f = x;
  unsigned r = v.u + 0x7fffu + ((v.u >> 16) & 1u);
  return (unsigned short)(r >> 16);
}
__device__ __forceinline__ unsigned cvt_pk(float lo, float hi) {
  unsigned r;
  asm("v_cvt_pk_bf16_f32 %0, %1, %2" : "=v"(r) : "v"(lo), "v"(hi));
  return r;
}
__device__ __forceinline__ float bfp_lo(unsigned p) { return __builtin_bit_cast(float, p << 16); }
__device__ __forceinline__ float bfp_hi(unsigned p) { return __builtin_bit_cast(float, p & 0xffff0000u); }
// s pre-scaled by log2e: sigmoid(x) = 1/(1+2^-s)
__device__ __forceinline__ float sigm_fast(float s) {
  return __builtin_amdgcn_rcpf(1.f + __builtin_amdgcn_exp2f(-s));
}
// y pre-scaled by 2*log2e: tanh(x) = 1 - 2/(1+2^y)
__device__ __forceinline__ float tanh_fast(float y) {
  return fmaf(-2.f, __builtin_amdgcn_rcpf(1.f + __builtin_amdgcn_exp2f(y)), 1.f);
}
__device__ __forceinline__ floatx4 splat4(float v) { floatx4 r; r[0]=v; r[1]=v; r[2]=v; r[3]=v; return r; }

#define N_WHH  (768*256)
#define N_WCAT (1024*256)
#define N_W1H  (256*256)
#define N_W2   (16*256)
#define N_TOT  (N_WHH + N_WCAT + N_W1H + N_W2)

#define GROW(r) (((((r)&7) ^ ((((r)>>3)&1)*5))) << 4)
#define A_SW(kk,q,row) ((((kk)<<6)+((q)<<4)) ^ GROW(row))

#define MF __builtin_amdgcn_mfma_f32_16x16x32_bf16

__global__ void prep_kernel(const float* __restrict__ w_hh, const float* __restrict__ w_ih,
                            const float* __restrict__ w1,  const float* __restrict__ w2,
                            unsigned short* __restrict__ Whh, unsigned short* __restrict__ Wcat,
                            unsigned short* __restrict__ W1h, unsigned short* __restrict__ W2b,
                            float* __restrict__ wzc) {
  int i = blockIdx.x * blockDim.x + threadIdx.x;
  if (i < N_WHH) {
    int n = i >> 8;
    Whh[i] = f2bf(w_hh[i] * (n < 512 ? LOG2E : TWO_LOG2E));
  } else if (i < N_WHH + N_WCAT) {
    int j = i - N_WHH; int n = j >> 8, k = j & 255;
    float v = 0.f;
    if (k < 208) {
      if (n < 768) v = w_ih[n * 209 + 1 + k] * (n < 512 ? LOG2E : TWO_LOG2E);
      else         v = w1[(n - 768) * 464 + 256 + k] * TWO_LOG2E;
    }
    Wcat[j] = f2bf(v);
  } else if (i < N_WHH + N_WCAT + N_W1H) {
    int j = i - N_WHH - N_WCAT; int n = j >> 8, k = j & 255;
    W1h[j] = f2bf(w1[n * 464 + k] * TWO_LOG2E);
  } else if (i < N_TOT) {
    int j = i - N_WHH - N_WCAT - N_W1H; int n = j >> 8, k = j & 255;
    W2b[j] = (n < 9) ? f2bf(w2[n * 256 + k]) : (unsigned short)0;
  } else if (i < N_TOT + 768) {
    int j = i - N_TOT;
    wzc[j] = w_ih[(size_t)j * 209] * (j < 512 ? LOG2E : TWO_LOG2E);
  }
}

__launch_bounds__(512, 1)
__global__ void const_kernel(const float* __restrict__ cc, const float* __restrict__ bb,
                             const float* __restrict__ mmat,
                             const float* __restrict__ b_ih, const float* __restrict__ b_hh,
                             const float* __restrict__ b1,
                             const unsigned short* __restrict__ Wcat,
                             float* __restrict__ CST, float* __restrict__ cnt,
                             float* __restrict__ cntmax) {
  __shared__ __align__(16) char smem[8192];
  const int tid = threadIdx.x;
  const int w = tid >> 6, l = tid & 63, q = l >> 4, li = l & 15;
  const int r0 = blockIdx.x << 4;

  {
    int row = tid >> 5, ch = tid & 31;
    float v[8];
#pragma unroll
    for (int j = 0; j < 8; j++) v[j] = 0.f;
    if (ch < 10) {
      const float* s = cc + (size_t)(r0 + row) * 80 + ch * 8;
#pragma unroll
      for (int j = 0; j < 8; j++) v[j] = s[j];
    } else if (ch < 18) {
      const float* s = bb + (size_t)(r0 + row) * 64 + (ch - 10) * 8;
#pragma unroll
      for (int j = 0; j < 8; j++) v[j] = s[j];
    } else if (ch < 26) {
      const float* s = mmat + (size_t)(r0 + row) * 64 + (ch - 18) * 8;
#pragma unroll
      for (int j = 0; j < 8; j++) v[j] = s[j];
    }
    short8 pk;
#pragma unroll
    for (int j = 0; j < 8; j++) pk[j] = (short)f2bf(v[j]);
    *(short8*)(smem + row * 512 + ((ch * 16) ^ GROW(row))) = pk;
  }
  __syncthreads();

  int col[8];
  floatx4 acc[8];
#pragma unroll
  for (int tt = 0; tt < 8; tt++) {
    col[tt] = (w * 8 + tt) * 16 + li;
    float bv;
    if (col[tt] < 512)      bv = LOG2E * (b_ih[col[tt]] + b_hh[col[tt]]);
    else if (col[tt] < 768) bv = TWO_LOG2E * b_ih[col[tt]];
    else                    bv = TWO_LOG2E * b1[col[tt] - 768];
    acc[tt] = splat4(bv);
  }
#pragma unroll
  for (int kk = 0; kk < 7; kk++) {
    short8 a = *(const short8*)(smem + li * 512 + A_SW(kk, q, li));
#pragma unroll
    for (int tt = 0; tt < 8; tt++) {
      short8 bf = *(const short8*)(Wcat + (size_t)col[tt] * 256 + kk * 32 + q * 8);
      acc[tt] = MF(a, bf, acc[tt], 0, 0, 0);
    }
  }
#pragma unroll
  for (int tt = 0; tt < 8; tt++)
#pragma unroll
    for (int r = 0; r < 4; r++)
      CST[(size_t)(r0 + q * 4 + r) * 1024 + col[tt]] = acc[tt][r];

  if (w == 0 && l < 16) {
    const float* bp = bb + (size_t)(r0 + l) * 64;
    const float* mp = mmat + (size_t)(r0 + l) * 64;
    float s = 0.f;
#pragma unroll 8
    for (int k2 = 0; k2 < 64; k2++) s += mp[k2] * (1.f - bp[k2]);
    cnt[r0 + l] = s;
    float mx = s;
#pragma unroll
    for (int off = 8; off; off >>= 1) mx = fmaxf(mx, __shfl_xor(mx, off, 16));
    if (l == 0) cntmax[blockIdx.x] = mx;
  }
}

// GRU scan v4 — transposed operands, ALL SIX weight tiles register-resident.
// LDS: H dbuf @0 2x8KB; zb @16384 4KB; per-thread const slots @20480, 512 x 144B
// (stride 144B = 36 dwords == 4 mod 32 -> conflict-free b128 reads).
// Total LDS 94208 > 81920 deliberately: caps occupancy at 1 block/CU so the
// scheduler targets 2 waves/EU (256-reg budget) and keeps the 192-reg weight
// set resident instead of sinking the loads into the loop (rounds 5/6 bug).
#define H_BASE 0
#define ZB_BASE 16384
#define CB_BASE 20480
#define GRU_LDS (20480 + 512 * 144)

__launch_bounds__(512, 1)
__global__ void gru_kernel(const float* __restrict__ z, const float* __restrict__ b_hh,
                           const unsigned short* __restrict__ Whh,
                           const float* __restrict__ wzc,
                           const float* __restrict__ CST,
                           const float* __restrict__ cntmax,
                           char* __restrict__ hs) {
  __shared__ __align__(16) char smem[GRU_LDS];
  const int tid = threadIdx.x;
  const int w = tid >> 6, l = tid & 63, q = l >> 4, li = l & 15;
  const int r0 = blockIdx.x << 4;
  const int nsteps = (int)(cntmax[blockIdx.x] + 0.5f);

  // zero h slot 0
  *(floatx4*)(smem + H_BASE + tid * 16) = splat4(0.f);
  // stage z transposed: zb[t*16+row]
  {
    float* zb = (float*)(smem + ZB_BASE);
    zb[tid] = z[(size_t)(r0 + (tid & 15)) * 64 + (tid >> 4)];
    int i1 = tid + 512;
    zb[i1] = z[(size_t)(r0 + (i1 & 15)) * 64 + (i1 >> 4)];
  }

  // weight A-frags, all resident: tiles (g,nc): 0=(r,0) 1=(r,1) 2=(z,0) 3=(z,1) 4=(n,0) 5=(n,1)
  short8 wa0[8], wa1[8], wa2[8], wa3[8], wa4[8], wa5[8];
  {
    const unsigned short* p0 = Whh + (size_t)((w << 5) + li) * 256 + q * 8;
    const unsigned short* p1 = Whh + (size_t)((w << 5) + 16 + li) * 256 + q * 8;
    const unsigned short* p2 = Whh + (size_t)(256 + (w << 5) + li) * 256 + q * 8;
    const unsigned short* p3 = Whh + (size_t)(256 + (w << 5) + 16 + li) * 256 + q * 8;
    const unsigned short* p4 = Whh + (size_t)(512 + (w << 5) + li) * 256 + q * 8;
    const unsigned short* p5 = Whh + (size_t)(512 + (w << 5) + 16 + li) * 256 + q * 8;
#pragma unroll
    for (int kk = 0; kk < 8; kk++) {
      wa0[kk] = *(const short8*)(p0 + kk * 32);
      wa1[kk] = *(const short8*)(p1 + kk * 32);
      wa2[kk] = *(const short8*)(p2 + kk * 32);
      wa3[kk] = *(const short8*)(p3 + kk * 32);
      wa4[kk] = *(const short8*)(p4 + kk * 32);
      wa5[kk] = *(const short8*)(p5 + kk * 32);
    }
  }

  // packed per-lane constants -> LDS slot (transposed: batch=li, gatecols = base+4q+{0..3})
  {
    const size_t crow = (size_t)(r0 + li) * 1024;
    unsigned* cb32 = (unsigned*)(smem + CB_BASE + tid * 144);
#pragma unroll
    for (int tt = 0; tt < 4; tt++) {
      int base = (tt >> 1) * 256 + (w << 5) + ((tt & 1) << 4) + (q << 2);
      floatx4 c = *(const floatx4*)(CST + crow + base);
      cb32[tt * 2]     = cvt_pk(c[0], c[1]);
      cb32[tt * 2 + 1] = cvt_pk(c[2], c[3]);
    }
#pragma unroll
    for (int nc = 0; nc < 2; nc++) {
      int base = 512 + (w << 5) + (nc << 4) + (q << 2);
      floatx4 c = *(const floatx4*)(CST + crow + base);
      cb32[8 + nc * 2]     = cvt_pk(c[0], c[1]);
      cb32[8 + nc * 2 + 1] = cvt_pk(c[2], c[3]);
      floatx4 b = *(const floatx4*)(b_hh + base);
      cb32[12 + nc * 2]     = cvt_pk(b[0] * TWO_LOG2E, b[1] * TWO_LOG2E);
      cb32[12 + nc * 2 + 1] = cvt_pk(b[2] * TWO_LOG2E, b[3] * TWO_LOG2E);
    }
#pragma unroll
    for (int tt = 0; tt < 6; tt++) {
      int base = (tt >> 1) * 256 + (w << 5) + ((tt & 1) << 4) + (q << 2);
      floatx4 c = *(const floatx4*)(wzc + base);
      cb32[16 + tt * 2]     = cvt_pk(c[0], c[1]);
      cb32[16 + tt * 2 + 1] = cvt_pk(c[2], c[3]);
    }
  }

  unsigned hpk[2][2] = {{0u, 0u}, {0u, 0u}};   // packed bf16 h (lane's 8 cols)

  __syncthreads();
  char* hs_blk = hs + (size_t)blockIdx.x * 524288;
  const char* CB = smem + CB_BASE + tid * 144;

#pragma unroll 1
  for (int t = 0; t < nsteps; t++) {
    const char* hp = smem + H_BASE + ((t & 1) << 13);
    char* hc = smem + H_BASE + (((t + 1) & 1) << 13);

    // accumulator init from LDS consts (crz for r,z tiles; 0 for n tiles)
    uint4v c0 = *(const uint4v*)(CB);
    uint4v c1 = *(const uint4v*)(CB + 16);
    floatx4 a0, a1, a2, a3, a4, a5;
    a0[0]=bfp_lo(c0[0]); a0[1]=bfp_hi(c0[0]); a0[2]=bfp_lo(c0[1]); a0[3]=bfp_hi(c0[1]);
    a1[0]=bfp_lo(c0[2]); a1[1]=bfp_hi(c0[2]); a1[2]=bfp_lo(c0[3]); a1[3]=bfp_hi(c0[3]);
    a2[0]=bfp_lo(c1[0]); a2[1]=bfp_hi(c1[0]); a2[2]=bfp_lo(c1[1]); a2[3]=bfp_hi(c1[1]);
    a3[0]=bfp_lo(c1[2]); a3[1]=bfp_hi(c1[2]); a3[2]=bfp_lo(c1[3]); a3[3]=bfp_hi(c1[3]);
    a4 = splat4(0.f); a5 = splat4(0.f);

#define LDH(kk) (*(const short8*)(hp + li * 512 + A_SW(kk, q, li)))
    short8 bA = LDH(0), bB = LDH(1);

#define KSTEP(kk, bX)                                                       \
    a0 = MF(wa0[kk], bX, a0, 0, 0, 0);                                      \
    a1 = MF(wa1[kk], bX, a1, 0, 0, 0);                                      \
    a2 = MF(wa2[kk], bX, a2, 0, 0, 0);                                      \
    a3 = MF(wa3[kk], bX, a3, 0, 0, 0);                                      \
    a4 = MF(wa4[kk], bX, a4, 0, 0, 0);                                      \
    a5 = MF(wa5[kk], bX, a5, 0, 0, 0);                                      \
    if ((kk) < 6) bX = LDH((kk) + 2);

    KSTEP(0, bA)
    KSTEP(1, bB)
    KSTEP(2, bA)
    KSTEP(3, bB)
    KSTEP(4, bA)
    KSTEP(5, bB)
    KSTEP(6, bA)
    KSTEP(7, bB)
#undef KSTEP
#undef LDH

    float zp = -1.f;
    if (t) zp = ((const float*)(smem + ZB_BASE))[(t - 1) * 16 + li];

    // gate-phase consts from LDS
    uint4v gcn = *(const uint4v*)(CB + 32);
    uint4v gbh = *(const uint4v*)(CB + 48);
    uint4v gw0 = *(const uint4v*)(CB + 64);
    uint4v gw1 = *(const uint4v*)(CB + 80);
    uint4v gw2 = *(const uint4v*)(CB + 96);

#define GATE(nc, pr, aR, aZ, aN)                                                    \
    {                                                                               \
      unsigned wzr = gw0[(nc) * 2 + (pr)];                                          \
      unsigned wzz = gw1[(nc) * 2 + (pr)];                                          \
      unsigned wzn = gw2[(nc) * 2 + (pr)];                                          \
      unsigned cnp = gcn[(nc) * 2 + (pr)];                                          \
      unsigned bhp = gbh[(nc) * 2 + (pr)];                                          \
      float rlo = sigm_fast(fmaf(zp, bfp_lo(wzr), aR[2 * (pr)]));                   \
      float rhi = sigm_fast(fmaf(zp, bfp_hi(wzr), aR[2 * (pr) + 1]));               \
      float zlo = sigm_fast(fmaf(zp, bfp_lo(wzz), aZ[2 * (pr)]));                   \
      float zhi = sigm_fast(fmaf(zp, bfp_hi(wzz), aZ[2 * (pr) + 1]));               \
      float gnlo = fmaf(zp, bfp_lo(wzn), bfp_lo(cnp));                              \
      float gnhi = fmaf(zp, bfp_hi(wzn), bfp_hi(cnp));                              \
      float nlo = tanh_fast(fmaf(rlo, aN[2 * (pr)] + bfp_lo(bhp), gnlo));           \
      float nhi = tanh_fast(fmaf(rhi, aN[2 * (pr) + 1] + bfp_hi(bhp), gnhi));       \
      unsigned hop = hpk[nc][pr];                                                   \
      float hlo = fmaf(zlo, bfp_lo(hop) - nlo, nlo);                                \
      float hhi = fmaf(zhi, bfp_hi(hop) - nhi, nhi);                                \
      unsigned np = cvt_pk(hlo, hhi);                                               \
      hpk[nc][pr] = np;                                                             \
      *(unsigned*)(hc + li * 512 +                                                  \
        (((w << 6) + ((nc) << 5) + (q << 3) + ((pr) << 2)) ^ GROW(li))) = np;       \
    }

    GATE(0, 0, a0, a2, a4)
    GATE(0, 1, a0, a2, a4)
    GATE(1, 0, a1, a3, a5)
    GATE(1, 1, a1, a3, a5)
#undef GATE

    __syncthreads();
    *(short8*)(hs_blk + (size_t)t * 8192 + tid * 16) = *(const short8*)(hc + tid * 16);
  }
}

// MLP + GMM. Grid 1024 = tg-outer (tg in {0..3}) x 256 rowgroups; t = tg + 4s.
// LDS: A dbuf @0 2x8KB, U dbuf @16384 2x8KB, P @32768 1088B, zb @33856 1KB
__launch_bounds__(512, 2)
__global__ void mlp_kernel(const float* __restrict__ z, const float* __restrict__ b2,
                           const float* __restrict__ cnt, const float* __restrict__ cntmax,
                           const unsigned short* __restrict__ W1h,
                           const unsigned short* __restrict__ W2b,
                           const float* __restrict__ CST, const char* __restrict__ hs,
                           float* __restrict__ out) {
  __shared__ __align__(16) char smem[34880];
  const int tid = threadIdx.x;
  const int w = tid >> 6, l = tid & 63, q = l >> 4, li = l & 15;
  const int tg = blockIdx.x >> 8, rg = blockIdx.x & 255;
  const int r0 = rg << 4;

  const int nsteps = (int)(cntmax[rg] + 0.5f);
  const int count = (nsteps - tg + 3) >> 2;
  if (count <= 0) return;
  const char* img = hs + (size_t)rg * 524288;

  // stage z tile transposed: zb[s*16+row] = z[row][tg+4s]
  if (tid < 256) {
    int s = tid >> 4, row = tid & 15;
    ((float*)(smem + 33856))[tid] = z[(size_t)(r0 + row) * 64 + tg + 4 * s];
  }

  int col[2];
#pragma unroll
  for (int nc = 0; nc < 2; nc++) col[nc] = (w << 5) + (nc << 4) + li;

  short8 w1reg[2][8];
#pragma unroll
  for (int nc = 0; nc < 2; nc++)
#pragma unroll
    for (int kk = 0; kk < 8; kk++)
      w1reg[nc][kk] = *(const short8*)(W1h + (size_t)col[nc] * 256 + kk * 32 + q * 8);

  float cst1[2][4];
#pragma unroll
  for (int nc = 0; nc < 2; nc++)
#pragma unroll
    for (int r = 0; r < 4; r++)
      cst1[nc][r] = CST[(size_t)(r0 + q * 4 + r) * 1024 + 768 + col[nc]];

  float b2v = (li < 9) ? b2[li] : 0.f;
  float cl = (l < 16) ? cnt[r0 + l] : 0.f;
  float lacc = 0.f;

  // stage A slot 0 (t = tg)
  {
    short8 v = *(const short8*)(img + (size_t)tg * 8192 + tid * 16);
    *(short8*)(smem + tid * 16) = v;
  }
  __syncthreads();

#pragma unroll 1
  for (int s = 0; s < count; s++) {
    int t = tg + 4 * s;
    // T14 split: issue next-image load now, ds_write after compute
    short8 pf;
    bool do_pf = (s + 1 < count);
    if (do_pf) pf = *(const short8*)(img + (size_t)(t + 4) * 8192 + tid * 16);

    floatx4 acc[2];
    acc[0] = splat4(0.f); acc[1] = splat4(0.f);
    const char* As = smem + (s & 1) * 8192;
#pragma unroll
    for (int kk = 0; kk < 8; kk++) {
      short8 a = *(const short8*)(As + li * 512 + A_SW(kk, q, li));
      acc[0] = MF(a, w1reg[0][kk], acc[0], 0, 0, 0);
      acc[1] = MF(a, w1reg[1][kk], acc[1], 0, 0, 0);
    }
    char* Us = smem + 16384 + (s & 1) * 8192;
#pragma unroll
    for (int nc = 0; nc < 2; nc++)
#pragma unroll
      for (int r = 0; r < 4; r++) {
        float uv = tanh_fast(acc[nc][r] + cst1[nc][r]);
        int rw = (q << 2) + r;
        int colb = col[nc] << 1;
        *(unsigned short*)(Us + rw * 512 + (colb ^ GROW(rw))) = f2bf(uv);
      }
    if (do_pf) *(short8*)(smem + ((s + 1) & 1) * 8192 + tid * 16) = pf;
    __syncthreads();

    if (w == (s & 7)) {   // duty wave: w2 GEMM + GMM epilogue
      floatx4 pacc = splat4(b2v);
#pragma unroll
      for (int kk = 0; kk < 8; kk++) {
        short8 au = *(const short8*)(Us + li * 512 + A_SW(kk, q, li));
        short8 bw = *(const short8*)(W2b + (size_t)li * 256 + kk * 32 + q * 8);
        pacc = MF(au, bw, pacc, 0, 0, 0);
      }
      float* Pw = (float*)(smem + 32768);
#pragma unroll
      for (int r = 0; r < 4; r++) Pw[((q << 2) + r) * 17 + li] = pacc[r];
      if (l < 16) {
        const float* pr = Pw + l * 17;
        float zt = ((const float*)(smem + 33856))[s * 16 + l];
        float aj[3], lg[3];
#pragma unroll
        for (int j = 0; j < 3; j++) {
          float lgt = pr[j];
          float mean = pr[3 + j];
          float ls = pr[6 + j];
          float d = (zt - mean) * __expf(-ls);
          lg[j] = lgt;
          aj[j] = lgt - ls - 0.9189385332f - 0.5f * d * d;
        }
        float mx = fmaxf(aj[0], fmaxf(aj[1], aj[2]));
        float ln_n = mx + __logf(__expf(aj[0] - mx) + __expf(aj[1] - mx) + __expf(aj[2] - mx));
        float mg = fmaxf(lg[0], fmaxf(lg[1], lg[2]));
        float ln_d = mg + __logf(__expf(lg[0] - mg) + __expf(lg[1] - mg) + __expf(lg[2] - mg));
        if ((float)t + 0.5f < cl) lacc += (ln_n - ln_d);
      }
    }
  }

  __syncthreads();
  if (l < 16) ((float*)(smem + 32768))[w * 16 + l] = lacc;
  __syncthreads();
  if (w == 0 && l < 16) {
    const float* F = (const float*)(smem + 32768);
    float s = 0.f;
#pragma unroll
    for (int ww = 0; ww < 8; ww++) s += F[ww * 16 + l];
    atomicAdd(&out[r0 + l], s);
  }
}

extern "C" void kernel_launch(void* const* d_in, const int* in_sizes, int n_in,
                              void* d_out, int out_size, void* d_ws, size_t ws_size,
                              hipStream_t stream) {
  const float* z    = (const float*)d_in[0];
  const float* c    = (const float*)d_in[1];
  const float* b    = (const float*)d_in[2];
  const float* m    = (const float*)d_in[3];
  const float* w_ih = (const float*)d_in[4];
  const float* w_hh = (const float*)d_in[5];
  const float* b_ih = (const float*)d_in[6];
  const float* b_hh = (const float*)d_in[7];
  const float* w1   = (const float*)d_in[8];
  const float* b1   = (const float*)d_in[9];
  const float* w2   = (const float*)d_in[10];
  const float* b2   = (const float*)d_in[11];

  char* ws = (char*)d_ws;
  unsigned short* Whh  = (unsigned short*)(ws);
  unsigned short* Wcat = (unsigned short*)(ws + 393216);
  unsigned short* W1h  = (unsigned short*)(ws + 917504);
  unsigned short* W2b  = (unsigned short*)(ws + 1048576);
  float*          CST  = (float*)(ws + 1056768);
  float*          cnt  = (float*)(ws + 17833984);
  float*          cmax = (float*)(ws + 17850368);
  float*          wzc  = (float*)(ws + 17851392);
  char*           hs   = ws + 17916928;

  hipMemsetAsync(d_out, 0, (size_t)out_size * sizeof(float), stream);
  hipLaunchKernelGGL(prep_kernel, dim3((N_TOT + 768) / 256), dim3(256), 0, stream,
                     w_hh, w_ih, w1, w2, Whh, Wcat, W1h, W2b, wzc);
  hipLaunchKernelGGL(const_kernel, dim3(256), dim3(512), 0, stream,
                     c, b, m, b_ih, b_hh, b1, Wcat, CST, cnt, cmax);
  hipLaunchKernelGGL(gru_kernel, dim3(256), dim3(512), 0, stream,
                     z, b_hh, Whh, wzc, CST, cmax, hs);
  hipLaunchKernelGGL(mlp_kernel, dim3(1024), dim3(512), 0, stream,
                     z, b2, cnt, cmax, W1h, W2b, CST, hs, (float*)d_out);
}